// Round 14
// baseline (48.251 us; speedup 1.0000x reference)
//
#include <hip/hip_runtime.h>

#define S      4096
#define CIN    7
#define DM     512
#define KERN   73
#define TT     512
#define TILES  (S / TT)        // 8
#define NSTAGE (TT + 17)       // 529 valid staged elements per channel row
#define TROW   532             // row stride (16B aligned; covers float4 overreads)
#define CHUNK  32
#define NCH    (TT / CHUNK)    // 16

#if __has_builtin(__builtin_amdgcn_fdot2) && __has_builtin(__builtin_amdgcn_cvt_pkrtz)
#define USE_DOT2 1
#else
#define USE_DOT2 0
#endif

typedef _Float16 half2_t __attribute__((ext_vector_type(2)));
typedef __fp16   half2_raw __attribute__((ext_vector_type(2)));

#if USE_DOT2
static __device__ __forceinline__ half2_t pkrtz(float a, float b) {
    half2_raw r = __builtin_amdgcn_cvt_pkrtz(a, b);
    return __builtin_bit_cast(half2_t, r);
}

// 18-tap FIR on 32 t via v_dot2_f32_f16: windows f16-packed once per chunk
// (aligned + odd-phase pair arrays), 9 dot2 per output, fp32 accumulate.
__device__ __forceinline__ void do_chunk32_dot2(const float* __restrict__ xc,
                                                const half2_t g2[9], float bias,
                                                float* __restrict__ opc)
{
    float w[52];
    #pragma unroll
    for (int q = 0; q < 13; ++q) {
        float4 v = *reinterpret_cast<const float4*>(xc + 4 * q);
        w[4*q+0] = v.x; w[4*q+1] = v.y; w[4*q+2] = v.z; w[4*q+3] = v.w;
    }
    half2_t A[26], B[25];
    #pragma unroll
    for (int p = 0; p < 26; ++p) A[p] = pkrtz(w[2*p], w[2*p+1]);
    #pragma unroll
    for (int p = 0; p < 25; ++p) B[p] = pkrtz(w[2*p+1], w[2*p+2]);

    #pragma unroll
    for (int i = 0; i < CHUNK; ++i) {
        float a = bias;
        const int p0 = i >> 1;
        if ((i & 1) == 0) {
            #pragma unroll
            for (int m = 0; m < 9; ++m)
                a = __builtin_amdgcn_fdot2(g2[m], A[p0 + m], a, false);
        } else {
            #pragma unroll
            for (int m = 0; m < 9; ++m)
                a = __builtin_amdgcn_fdot2(g2[m], B[p0 + m], a, false);
        }
        opc[i * DM] = a;   // store as soon as this output finishes
    }
}
#endif

// fp32 scalar fallback path (R8 structure)
__device__ __forceinline__ void do_chunk32_fma(const float* __restrict__ xc,
                                               const float g[18], float bias,
                                               float* __restrict__ opc)
{
    float acc[CHUNK];
    #pragma unroll
    for (int i = 0; i < CHUNK; ++i) acc[i] = bias;
    #pragma unroll
    for (int q = 0; q < 13; ++q) {
        float4 v = *reinterpret_cast<const float4*>(xc + 4 * q);
        float va[4] = {v.x, v.y, v.z, v.w};
        #pragma unroll
        for (int e = 0; e < 4; ++e) {
            const int j = 4 * q + e;
            #pragma unroll
            for (int i = 0; i < CHUNK; ++i) {
                const int off = j - i;
                if (off >= 0 && off < 18)
                    acc[i] = fmaf(g[off], va[e], acc[i]);
            }
        }
        if (q >= 4 && q < 12) {
            const int lo = (q == 4) ? 0 : (4 * q - 17);
            const int hi = 4 * q - 14;
            #pragma unroll
            for (int i = 0; i < CHUNK; ++i)
                if (i >= lo && i <= hi) opc[i * DM] = acc[i];
        }
        if (q == 12) opc[31 * DM] = acc[31];
    }
}

__global__ __launch_bounds__(512, 2)
void tokemb_kernel(const float* __restrict__ x,
                   const float* __restrict__ w_conv,
                   const float* __restrict__ b_conv,
                   const float* __restrict__ w_left,
                   const float* __restrict__ b_left,
                   float* __restrict__ out)
{
    __shared__ float xs[CIN * TROW];

    const int blk  = blockIdx.x;
    const int b    = blk / TILES;
    const int tile = blk & (TILES - 1);
    const int t0   = tile * TT;
    const int tid  = threadIdx.x;

    // ---- stage x tile into LDS transposed: xs[c][j] = x[b, (t0-16+j) mod S, c]
    {
        const float* xb = x + (long long)b * S * CIN;
        const long long base = (long long)(t0 - 16) * CIN;
        const int nfl = CIN * NSTAGE;                        // 3703 floats
        for (int e4 = 4 * tid; e4 < nfl; e4 += 4 * 512) {
            long long src = base + e4;
            if (src >= 0 && src + 3 < (long long)S * CIN) {
                float4 v = *reinterpret_cast<const float4*>(xb + src);
                float va[4] = {v.x, v.y, v.z, v.w};
                #pragma unroll
                for (int u = 0; u < 4; ++u) {
                    int e = e4 + u;
                    int j = e / CIN, c = e - j * CIN;
                    xs[c * TROW + j] = va[u];
                }
            } else {
                #pragma unroll
                for (int u = 0; u < 4; ++u) {
                    int e = e4 + u;
                    if (e < nfl) {
                        int j = e / CIN, c = e - j * CIN;
                        int tm = t0 - 16 + j;
                        if (tm < 0) tm += S; else if (tm >= S) tm -= S;
                        xs[c * TROW + j] = xb[tm * CIN + c];
                    }
                }
            }
        }
    }

    // ---- per-thread weights in FIR tap order ----
    const int d  = tid;
    const int oo = d % KERN;
    const float* wrow = (d < DM - 1) ? (w_conv + oo * 18) : w_left;
    const float bias  = (d < DM - 1) ? b_conv[oo] : b_left[0];
    const int cc = (d < DM - 1) ? (d / KERN) : (CIN - 1);
    float g[18];
    #pragma unroll
    for (int off = 0; off < 18; ++off)
        g[off] = wrow[(5 - off / 3) * 3 + (off % 3)];
#if USE_DOT2
    half2_t g2[9];
    #pragma unroll
    for (int m = 0; m < 9; ++m)
        g2[m] = pkrtz(g[2*m], g[2*m+1]);
#endif

    __syncthreads();

    const float* xrow = xs + cc * TROW;
    float* const op = out + ((long long)b * S + t0) * DM + d;

    const bool edgetile = (tile == 0) || (tile == TILES - 1);

    for (int cc_ = 0; cc_ < NCH; ++cc_) {
        const int jb  = cc_ * CHUNK;
        const int tc  = t0 + jb;
        float* opc = op + jb * DM;

        if (!edgetile || !((tc < 16) || (tc + CHUNK >= S))) {
#if USE_DOT2
            do_chunk32_dot2(xrow + jb, g2, bias, opc);
#else
            do_chunk32_fma(xrow + jb, g, bias, opc);
#endif
        } else {
            // masked exact fp32 path (tile 0 chunk 0, tile 7 chunk 15 only)
            #pragma unroll
            for (int i = 0; i < CHUNK; ++i) {
                float p0 = 0.f, p1 = 0.f, p2 = 0.f;
                #pragma unroll
                for (int o = 0; o < 18; o += 3) {
                    p0 = fmaf(g[o],     xrow[jb + i + o],     p0);
                    p1 = fmaf(g[o + 1], xrow[jb + i + o + 1], p1);
                    p2 = fmaf(g[o + 2], xrow[jb + i + o + 2], p2);
                }
                const int t = tc + i;
                const float f0 = (t == 0 || t >= 16)     ? 1.f : 0.f;
                const float f1 = (t >= 15)               ? 1.f : 0.f;
                const float f2 = (t >= 14 && t != S - 1) ? 1.f : 0.f;
                opc[i * DM] = bias + f0 * p0 + f1 * p1 + f2 * p2;
            }
        }
    }
}

extern "C" void kernel_launch(void* const* d_in, const int* in_sizes, int n_in,
                              void* d_out, int out_size, void* d_ws, size_t ws_size,
                              hipStream_t stream) {
    const float* x      = (const float*)d_in[0];
    const float* w_conv = (const float*)d_in[1];
    const float* b_conv = (const float*)d_in[2];
    const float* w_left = (const float*)d_in[3];
    const float* b_left = (const float*)d_in[4];
    float* out = (float*)d_out;

    const int B = in_sizes[0] / (S * CIN);   // 32
    dim3 grid(B * TILES);                    // 256 blocks = 1 per CU
    tokemb_kernel<<<grid, 512, 0, stream>>>(x, w_conv, b_conv, w_left, b_left, out);
}